// Round 14
// baseline (143.876 us; speedup 1.0000x reference)
//
#include <hip/hip_runtime.h>
#include <hip/hip_bf16.h>

#define GAMMA 0.9865f

typedef __attribute__((ext_vector_type(8))) short bf16x8;
typedef __attribute__((ext_vector_type(4))) float f32x4;

static constexpr int Bb  = 8;
static constexpr int Tt  = 2048;
static constexpr int DIN = 1024;
static constexpr int Dd  = 1024;
static constexpr int Mm  = Bb * Tt;      // 16384
static constexpr int CL  = 64;           // chunk length for scan
static constexpr int NC  = Tt / CL;      // 32 chunks
static constexpr int NT  = DIN / 64;     // 16 K-tiles of BK=64

__device__ __forceinline__ void gload16(const void* g, void* l) {
  __builtin_amdgcn_global_load_lds(
      (const __attribute__((address_space(1))) void*)g,
      (__attribute__((address_space(3))) void*)l, 16, 0, 0);
}

__device__ __forceinline__ void bar() {
  asm volatile("" ::: "memory");
  __builtin_amdgcn_s_barrier();
  asm volatile("" ::: "memory");
}

__device__ __forceinline__ float bf16_to_f32(unsigned short u) {
  return __uint_as_float(((unsigned int)u) << 16);
}

// ---- K1: merged prep: wsum (blocks 0..255) + Wt transpose (256..2303) ----
__global__ __launch_bounds__(256) void prep_kernel(
    const float* __restrict__ Wq, const float* __restrict__ Wk,
    const float* __restrict__ Wv, float* __restrict__ wsum,
    __hip_bfloat16* __restrict__ Wt) {
  int bid = blockIdx.x;
  if (bid < 256) {
    int row  = bid * 4 + (threadIdx.x >> 6);
    int lane = threadIdx.x & 63;
    const float4* rp = (const float4*)(Wk + (size_t)row * DIN);
    float s = 0.f;
#pragma unroll
    for (int i = 0; i < 4; ++i) {
      float4 v = rp[lane + i * 64];
      s += v.x + v.y + v.z + v.w;
    }
    for (int off = 32; off; off >>= 1) s += __shfl_down(s, off);
    if (lane == 0) wsum[row] = s;
    return;
  }
  int wid = bid - 256;
  int z = wid >> 10, rem = wid & 1023;
  int kb = rem & 31, nb = rem >> 5;
  const float* W = z ? Wv : Wq;
  __hip_bfloat16* outp = Wt + (size_t)z * DIN * Dd;
  __shared__ float tile[32][33];
  int k0 = kb * 32, n0 = nb * 32;
  int tx = threadIdx.x & 31, ty = threadIdx.x >> 5;
#pragma unroll
  for (int i = 0; i < 4; ++i)
    tile[ty + i * 8][tx] = W[(size_t)(k0 + ty + i * 8) * Dd + n0 + tx];
  __syncthreads();
#pragma unroll
  for (int i = 0; i < 4; ++i)
    outp[(size_t)(n0 + ty + i * 8) * DIN + k0 + tx] =
        __float2bfloat16(tile[tx][ty + i * 8]);
}

// ---- K2: merged cast (y=0,1) + ksum (y=2) — at HBM floor -----------------
__global__ __launch_bounds__(256) void castksum_kernel(
    const float* __restrict__ xq, const float* __restrict__ xk,
    const float* __restrict__ xv, const float* __restrict__ wsum,
    __hip_bfloat16* __restrict__ oq, __hip_bfloat16* __restrict__ ov,
    float* __restrict__ ksum) {
  int y = blockIdx.y;
  if (y < 2) {
    const float* src = y ? xv : xq;
    __hip_bfloat16* dst = y ? ov : oq;
    size_t i = (size_t)blockIdx.x * 256 + threadIdx.x;
    const float4* p = (const float4*)src;
    float4 a = p[i * 2], b = p[i * 2 + 1];
    union { __hip_bfloat16 h[8]; bf16x8 v; } u;
    u.h[0] = __float2bfloat16(a.x); u.h[1] = __float2bfloat16(a.y);
    u.h[2] = __float2bfloat16(a.z); u.h[3] = __float2bfloat16(a.w);
    u.h[4] = __float2bfloat16(b.x); u.h[5] = __float2bfloat16(b.y);
    u.h[6] = __float2bfloat16(b.z); u.h[7] = __float2bfloat16(b.w);
    ((bf16x8*)dst)[i] = u.v;
    return;
  }
  if (blockIdx.x >= Mm / 4) return;
  int row  = blockIdx.x * 4 + (threadIdx.x >> 6);
  int lane = threadIdx.x & 63;
  const float4* rp = (const float4*)(xk + (size_t)row * DIN);
  const float4* wp = (const float4*)wsum;
  float s = 0.f;
#pragma unroll
  for (int i = 0; i < 4; ++i) {
    float4 a = rp[lane + i * 64];
    float4 w = wp[lane + i * 64];
    s += a.x * w.x + a.y * w.y + a.z * w.z + a.w * w.w;
  }
  for (int off = 32; off; off >>= 1) s += __shfl_down(s, off);
  if (lane == 0) ksum[row] = s;
}

// ---- GEMM core: R7-verified 8-phase K-loop (conflicts=0, vmcnt(4)/tile) --
// STAGEV: at t=NT-1, stage the 256x256 V-tile into the dying buffers —
// half0 -> buf0 in P0's empty staging slot (buf0 dead after t=14's last bar),
// half1 -> buf1 in P3's empty slot (buf1's last ds_read done before P2's
// first bar). t=15 has NO intermediate vmcnt -> counted ledger untouched;
// caller drains with vmcnt(0) after the loop.
__device__ __forceinline__ void stage_half(const __hip_bfloat16* g, char* l, int tid) {
#pragma unroll
  for (int j = 0; j < 2; ++j) {
    int c = tid + j * 512;
    int row = c >> 3, ch = c & 7;
    gload16(g + (size_t)row * DIN + ((ch ^ (row & 7)) << 3), l + c * 16);
  }
}

__device__ __forceinline__ void stageV_half(const __hip_bfloat16* Vt, char* lds,
                                            int tid, int h) {
#pragma unroll
  for (int j = 0; j < 8; ++j) {
    int c = tid + (h * 8 + j) * 512;
    int row = c >> 5, sl = c & 31;
    int chn = sl ^ (row & 7);
    gload16(Vt + (size_t)row * Dd + chn * 8, lds + c * 16);
  }
}

__device__ __forceinline__ bf16x8 lds_frag(const char* base, int row, int kc) {
  return *(const bf16x8*)(base + (((row << 3) + (kc ^ (row & 7))) << 4));
}

#define MFMA_QUAD(MLO, NLO)                                                  \
  _Pragma("unroll") for (int mi = 0; mi < 4; ++mi)                           \
  _Pragma("unroll") for (int ni = 0; ni < 2; ++ni)                           \
  _Pragma("unroll") for (int ks = 0; ks < 2; ++ks)                           \
      acc[(MLO) + mi][(NLO) + ni] = __builtin_amdgcn_mfma_f32_16x16x32_bf16( \
          a[(MLO) + mi][ks], b[(NLO) + ni][ks], acc[(MLO) + mi][(NLO) + ni], 0, 0, 0);

template <bool STAGEV>
__device__ __forceinline__ void gemm_core(const __hip_bfloat16* Ag,
                                          const __hip_bfloat16* Bg,
                                          const __hip_bfloat16* Vt, char* lds,
                                          int tid, int wm, int wn, int fq, int fr,
                                          f32x4 (&acc)[8][4]) {
  stage_half(Ag,                  lds,                 tid);
  stage_half(Ag + 128 * DIN,      lds + 16384,         tid);
  stage_half(Bg,                  lds + 32768,         tid);
  stage_half(Bg + 128 * DIN,      lds + 49152,         tid);
  stage_half(Ag + 64,             lds + 65536,         tid);
  stage_half(Ag + 128 * DIN + 64, lds + 65536 + 16384, tid);
  asm volatile("s_waitcnt vmcnt(4)" ::: "memory");
  bar();

  for (int t = 0; t < NT; ++t) {
    char* buf  = lds + (t & 1) * 65536;
    char* bufN = lds + ((t + 1) & 1) * 65536;
    const char* At = buf;
    const char* Bt = buf + 32768;
    bf16x8 a[8][2], b[4][2];

    // ---- P0: read a[0..3], b[0..1]; stage B(t+1)h0  (t=15: V half0)
#pragma unroll
    for (int mi = 0; mi < 4; ++mi)
#pragma unroll
      for (int ks = 0; ks < 2; ++ks)
        a[mi][ks] = lds_frag(At, wm + mi * 16 + fr, ks * 4 + fq);
#pragma unroll
    for (int ni = 0; ni < 2; ++ni)
#pragma unroll
      for (int ks = 0; ks < 2; ++ks)
        b[ni][ks] = lds_frag(Bt, wn + ni * 16 + fr, ks * 4 + fq);
    if (t + 1 < NT) stage_half(Bg + (size_t)(t + 1) * 64, bufN + 32768, tid);
    else if (STAGEV) stageV_half(Vt, lds, tid, 0);   // -> buf0 (dead)
    bar();
    __builtin_amdgcn_s_setprio(1);
    MFMA_QUAD(0, 0);
    __builtin_amdgcn_s_setprio(0);
    bar();

    // ---- P1: read a[4..7]; stage B(t+1)h1
#pragma unroll
    for (int mi = 4; mi < 8; ++mi)
#pragma unroll
      for (int ks = 0; ks < 2; ++ks)
        a[mi][ks] = lds_frag(At, wm + mi * 16 + fr, ks * 4 + fq);
    if (t + 1 < NT)
      stage_half(Bg + 128 * DIN + (size_t)(t + 1) * 64, bufN + 49152, tid);
    bar();
    __builtin_amdgcn_s_setprio(1);
    MFMA_QUAD(4, 0);
    __builtin_amdgcn_s_setprio(0);
    bar();

    // ---- P2: read b[2..3]; stage A(t+2)h0 into buf (A dead after P1)
#pragma unroll
    for (int ni = 2; ni < 4; ++ni)
#pragma unroll
      for (int ks = 0; ks < 2; ++ks)
        b[ni][ks] = lds_frag(Bt, wn + ni * 16 + fr, ks * 4 + fq);
    if (t + 2 < NT) stage_half(Ag + (size_t)(t + 2) * 64, buf, tid);
    bar();
    __builtin_amdgcn_s_setprio(1);
    MFMA_QUAD(0, 2);
    __builtin_amdgcn_s_setprio(0);
    bar();

    // ---- P3: stage A(t+2)h1; counted vmcnt once per tile (t=15: V half1)
    if (t + 2 < NT)
      stage_half(Ag + 128 * DIN + (size_t)(t + 2) * 64, buf + 16384, tid);
    else if (STAGEV && t + 1 >= NT)
      stageV_half(Vt, lds, tid, 1);                  // -> buf1 (reads done)
    if (t + 1 < NT) {
      if (t + 2 < NT) asm volatile("s_waitcnt vmcnt(4)" ::: "memory");
      else            asm volatile("s_waitcnt vmcnt(0)" ::: "memory");
    }
    bar();
    __builtin_amdgcn_s_setprio(1);
    MFMA_QUAD(4, 2);
    __builtin_amdgcn_s_setprio(0);
    bar();
  }
}

// ---- K3a: V GEMM + fused scanA epilogue (grid 256) — R13 verified --------
__global__ __launch_bounds__(512, 2) void gemmV_kernel(
    const __hip_bfloat16* __restrict__ Av, const __hip_bfloat16* __restrict__ Wt,
    const float* __restrict__ ksum, __hip_bfloat16* __restrict__ Vbf,
    float* __restrict__ E) {
  extern __shared__ char lds[];
  int lin = blockIdx.x;
  int wg  = (lin & 7) * 32 + (lin >> 3);   // 256 blocks, bijective
  int by  = wg & 3, bx = wg >> 2;
  const int m0 = bx * 256, n0 = by * 256;
  const __hip_bfloat16* Ag = Av + (size_t)m0 * DIN;
  const __hip_bfloat16* Bg = Wt + ((size_t)Dd + n0) * DIN;  // Wv half

  const int tid = threadIdx.x;
  const int wv = tid >> 6, lane = tid & 63;
  const int wm = (wv >> 2) * 128, wn = (wv & 3) * 64;
  const int fq = lane >> 4, fr = lane & 15;

  f32x4 acc[8][4] = {};
  gemm_core<false>(Ag, Bg, nullptr, lds, tid, wm, wn, fq, fr, acc);

  // global store + LDS stash (bf16, swizzled)
#pragma unroll
  for (int mi = 0; mi < 8; ++mi) {
#pragma unroll
    for (int ni = 0; ni < 4; ++ni) {
      f32x4 v = acc[mi][ni];
      int row = wm + mi * 16 + fq * 4;
      int col = wn + ni * 16 + fr;
#pragma unroll
      for (int j = 0; j < 4; ++j) {
        int r = row + j;
        unsigned short h = __bfloat16_as_ushort(__float2bfloat16(v[j]));
        Vbf[(size_t)(m0 + r) * Dd + n0 + col] = __ushort_as_bfloat16(h);
        *(unsigned short*)(lds + r * 512 + ((col * 2) ^ ((r & 7) << 4))) = h;
      }
    }
  }
  bar();

  // in-tile chunk scans -> E  (1024 tasks = 4 chunks x 256 cols, 2/thread)
  const int b = m0 >> 11, t0 = m0 & 2047;
#pragma unroll
  for (int p = 0; p < 2; ++p) {
    int task = tid + p * 512;
    int col = task & 255, cc = task >> 8;
    const float* kp = ksum + (size_t)b * Tt + t0 + cc * 64;
    float s = 0.f;
    for (int i = 0; i < CL; ++i) {
      int t = cc * 64 + i;
      float v = bf16_to_f32(
          *(const unsigned short*)(lds + t * 512 + ((col * 2) ^ ((t & 7) << 4))));
      float kv = kp[i];
      if (t0 == 0 && cc == 0 && i == 0) kv = 0.f;
      s = s * GAMMA + kv * v;
    }
    E[((size_t)b * NC + (t0 >> 6) + cc) * Dd + n0 + col] = s;
  }
}

// ---- K3b: Q GEMM + fused scanB (carry from E) + scan + final -------------
__global__ __launch_bounds__(512, 2) void gemmQ_kernel(
    const __hip_bfloat16* __restrict__ Aq, const __hip_bfloat16* __restrict__ Wt,
    const __hip_bfloat16* __restrict__ Vbf, const float* __restrict__ ksum,
    const float* __restrict__ E, float gCL, float* __restrict__ outp) {
  extern __shared__ char lds[];
  int lin = blockIdx.x;
  int wg  = (lin & 7) * 32 + (lin >> 3);
  int by  = wg & 3, bx = wg >> 2;
  const int m0 = bx * 256, n0 = by * 256;
  const __hip_bfloat16* Ag = Aq + (size_t)m0 * DIN;
  const __hip_bfloat16* Bg = Wt + (size_t)n0 * DIN;  // Wq half
  const int b = m0 >> 11, t0 = m0 & 2047;

  const int tid = threadIdx.x;
  const int wv = tid >> 6, lane = tid & 63;
  const int wm = (wv >> 2) * 128, wn = (wv & 3) * 64;
  const int fq = lane >> 4, fr = lane & 15;

  // --- fused scanB: compose this thread's 2 carries from E (L3-hot, 1MB).
  // C = 4*(bx&7)+cc is wave-uniform; same fp32 order as the old scanB.
  float carryR[2];
  {
    const int cbase = t0 >> 6;
#pragma unroll
    for (int p = 0; p < 2; ++p) {
      int task = tid + p * 512;
      int col = task & 255, cc = task >> 8;
      int C = cbase + cc;
      float s = 0.f;
      for (int j = 0; j < C; ++j)
        s = E[((size_t)b * NC + j) * Dd + n0 + col] + gCL * s;
      carryR[p] = s;
    }
  }

  f32x4 acc[8][4] = {};
  gemm_core<true>(Ag, Bg, Vbf + (size_t)m0 * Dd + n0, lds,
                  tid, wm, wn, fq, fr, acc);

  // V already staged into LDS during t=NT-1; drain DMA and sync.
  asm volatile("s_waitcnt vmcnt(0)" ::: "memory");
  bar();

  // --- in-tile scan with carry, S stored bf16 in place ---
#pragma unroll
  for (int p = 0; p < 2; ++p) {
    int task = tid + p * 512;
    int col = task & 255, cc = task >> 8;
    float s = carryR[p];
    const float* kp = ksum + (size_t)b * Tt + t0 + cc * 64;
    for (int i = 0; i < CL; ++i) {
      int t = cc * 64 + i;
      int addr = t * 512 + ((col * 2) ^ ((t & 7) << 4));
      unsigned short* sp = (unsigned short*)(lds + addr);
      float v = bf16_to_f32(*sp);
      float kv = kp[i];
      if (t0 == 0 && cc == 0 && i == 0) kv = 0.f;
      s = s * GAMMA + kv * v;
      *sp = __bfloat16_as_ushort(__float2bfloat16(s));
    }
  }
  bar();

  // --- out = Q * S, fp32 ---
#pragma unroll
  for (int mi = 0; mi < 8; ++mi) {
#pragma unroll
    for (int ni = 0; ni < 4; ++ni) {
      f32x4 v = acc[mi][ni];
      int row = wm + mi * 16 + fq * 4;
      int col = wn + ni * 16 + fr;
#pragma unroll
      for (int j = 0; j < 4; ++j) {
        int r = row + j;
        float S = bf16_to_f32(
            *(const unsigned short*)(lds + r * 512 + ((col * 2) ^ ((r & 7) << 4))));
        outp[(size_t)(m0 + r) * Dd + n0 + col] = v[j] * S;
      }
    }
  }
}

extern "C" void kernel_launch(void* const* d_in, const int* in_sizes, int n_in,
                              void* d_out, int out_size, void* d_ws, size_t ws_size,
                              hipStream_t stream) {
  (void)in_sizes; (void)n_in; (void)out_size; (void)ws_size;
  const float* xq = (const float*)d_in[0];
  const float* xk = (const float*)d_in[1];
  const float* xv = (const float*)d_in[2];
  const float* Wq = (const float*)d_in[3];
  const float* Wk = (const float*)d_in[4];
  const float* Wv = (const float*)d_in[5];
  float* outp = (float*)d_out;

  char* ws = (char*)d_ws;
  size_t off = 0;
  auto alloc = [&](size_t bytes) {
    char* p = ws + off;
    off += (bytes + 255) & ~(size_t)255;
    return p;
  };
  __hip_bfloat16* xq_bf = (__hip_bfloat16*)alloc((size_t)Mm * DIN * 2);
  __hip_bfloat16* xv_bf = (__hip_bfloat16*)alloc((size_t)Mm * DIN * 2);
  __hip_bfloat16* Wt    = (__hip_bfloat16*)alloc((size_t)2 * DIN * Dd * 2);
  __hip_bfloat16* Vbf   = (__hip_bfloat16*)alloc((size_t)Mm * Dd * 2);
  float* wsum  = (float*)alloc((size_t)DIN * 4);
  float* ksum  = (float*)alloc((size_t)Mm * 4);
  float* E     = (float*)alloc((size_t)Bb * NC * Dd * 4);

  double g = 1.0;
  for (int i = 0; i < CL; ++i) g *= (double)GAMMA;
  float gCL = (float)g;

  (void)hipFuncSetAttribute((const void*)gemmV_kernel,
                            hipFuncAttributeMaxDynamicSharedMemorySize, 131072);
  (void)hipFuncSetAttribute((const void*)gemmQ_kernel,
                            hipFuncAttributeMaxDynamicSharedMemorySize, 131072);

  prep_kernel<<<256 + 2048, 256, 0, stream>>>(Wq, Wk, Wv, wsum, Wt);
  castksum_kernel<<<dim3(Mm * DIN / 8 / 256, 3), 256, 0, stream>>>(
      xq, xk, xv, wsum, xq_bf, xv_bf, ksum);
  gemmV_kernel<<<256, 512, 131072, stream>>>(xv_bf, Wt, ksum, Vbf, E);
  gemmQ_kernel<<<256, 512, 131072, stream>>>(xq_bf, Wt, Vbf, ksum, E, gCL, outp);
}